// Round 1
// baseline (92368.958 us; speedup 1.0000x reference)
//
#include <hip/hip_runtime.h>
#include <hip/hip_bf16.h>
#include <math.h>

// Problem dims
#define BB 256
#define TT 512
#define INW 128
#define EH 512
#define GH 512

// Grid decomposition: 8 batch groups x 32 column-slice blocks = 256 blocks (1/CU)
#define NGROUP 8
#define NGB 32          // blocks per group (column slices)
#define MB 32           // batch rows per group
#define NB 16           // hidden columns per block

#define WPAD 516        // padded LDS stride (floats) for K=512 weights: (4j+k)%32 spreads banks, 16B aligned
#define XPAD 132        // padded LDS stride for K=128 weights

__device__ __forceinline__ float dot4(float4 a, float4 b) {
    return a.x*b.x + a.y*b.y + a.z*b.z + a.w*b.w;
}
__device__ __forceinline__ float sigm(float x) { return 1.0f / (1.0f + __expf(-x)); }

// Cross-block (within batch-group) barrier: monotonic counter, release/acquire at agent scope.
__device__ __forceinline__ void grp_sync(unsigned* cnt, unsigned target) {
    __threadfence();          // release my global writes to agent scope
    __syncthreads();          // whole block done writing + fenced
    if (threadIdx.x == 0) {
        __hip_atomic_fetch_add(cnt, 1u, __ATOMIC_RELEASE, __HIP_MEMORY_SCOPE_AGENT);
        long spins = 0;
        while (__hip_atomic_load(cnt, __ATOMIC_RELAXED, __HIP_MEMORY_SCOPE_AGENT) < target) {
            __builtin_amdgcn_s_sleep(1);
            if (++spins > (1L << 22)) break;   // deadlock escape hatch (never hit legitimately)
        }
    }
    __syncthreads();
    __threadfence();          // acquire side: see other blocks' writes
}

// ---------------- Encoder: 512-step GRU, h kept in global ping-pong, weights resident in LDS ----------
__global__ __launch_bounds__(256, 1) void enc_kernel(
    const float* __restrict__ src,     // [B,T,IN]
    const float* __restrict__ Wi,      // [3*EH, IN] rows: r,z,n
    const float* __restrict__ Wh,      // [3*EH, EH]
    float*       __restrict__ hbuf,    // [2, B, EH] ping-pong, slot0 pre-zeroed
    unsigned*    __restrict__ bars)
{
    __shared__ float sWh[3][NB][WPAD];
    __shared__ float sWi[3][NB][XPAD];

    const int bid = blockIdx.x;
    const int g   = bid / NGB;     // batch group
    const int ng  = bid % NGB;     // column slice
    const int tid = threadIdx.x;
    const int j0  = ng * NB;

    // Load persistent weight slices into LDS (rows j0..j0+NB-1 of each gate block)
    for (int gg = 0; gg < 3; ++gg) {
        for (int idx = tid; idx < NB * (EH/4); idx += 256) {
            int jj = idx >> 7;          // EH/4 = 128 float4 per row
            int k4 = idx & 127;
            float4 v = ((const float4*)(Wh + (size_t)(gg*EH + j0 + jj) * EH))[k4];
            *(float4*)&sWh[gg][jj][k4*4] = v;
        }
        for (int idx = tid; idx < NB * (INW/4); idx += 256) {
            int jj = idx >> 5;          // IN/4 = 32 float4 per row
            int k4 = idx & 31;
            float4 v = ((const float4*)(Wi + (size_t)(gg*EH + j0 + jj) * INW))[k4];
            *(float4*)&sWi[gg][jj][k4*4] = v;
        }
    }
    __syncthreads();

    const int bp = tid >> 4;               // 0..15 -> pair of batch rows
    const int j  = tid & 15;               // column within slice
    const int b0 = g*MB + bp*2, b1 = b0 + 1;
    const int jc = j0 + j;

    unsigned* cnt = bars + g * 32;         // 128B-spaced counter per group
    float* s0 = hbuf;
    float* s1 = hbuf + (size_t)BB * EH;

    const float4* wrx = (const float4*)&sWi[0][j][0];
    const float4* wzx = (const float4*)&sWi[1][j][0];
    const float4* wnx = (const float4*)&sWi[2][j][0];
    const float4* wrh = (const float4*)&sWh[0][j][0];
    const float4* wzh = (const float4*)&sWh[1][j][0];
    const float4* wnh = (const float4*)&sWh[2][j][0];

    for (int t = 0; t < TT; ++t) {
        const float* hc = (t & 1) ? s1 : s0;
        float*       hn = (t & 1) ? s0 : s1;

        // input projection (xr, xz, xn kept separate from h-parts; n needs r*hn)
        float axr0=0.f, axz0=0.f, axn0=0.f, axr1=0.f, axz1=0.f, axn1=0.f;
        const float4* x0 = (const float4*)(src + ((size_t)b0*TT + t) * INW);
        const float4* x1 = (const float4*)(src + ((size_t)b1*TT + t) * INW);
        #pragma unroll 4
        for (int k4 = 0; k4 < INW/4; ++k4) {
            float4 a0 = x0[k4], a1 = x1[k4];
            float4 r = wrx[k4], z = wzx[k4], n = wnx[k4];
            axr0 += dot4(a0,r); axz0 += dot4(a0,z); axn0 += dot4(a0,n);
            axr1 += dot4(a1,r); axz1 += dot4(a1,z); axn1 += dot4(a1,n);
        }

        float hp0 = hc[(size_t)b0*EH + jc];
        float hp1 = hc[(size_t)b1*EH + jc];

        float ahr0=0.f, ahz0=0.f, ahn0=0.f, ahr1=0.f, ahz1=0.f, ahn1=0.f;
        const float4* h0p = (const float4*)(hc + (size_t)b0*EH);
        const float4* h1p = (const float4*)(hc + (size_t)b1*EH);
        #pragma unroll 4
        for (int k4 = 0; k4 < EH/4; ++k4) {
            float4 a0 = h0p[k4], a1 = h1p[k4];
            float4 r = wrh[k4], z = wzh[k4], n = wnh[k4];
            ahr0 += dot4(a0,r); ahz0 += dot4(a0,z); ahn0 += dot4(a0,n);
            ahr1 += dot4(a1,r); ahz1 += dot4(a1,z); ahn1 += dot4(a1,n);
        }

        float r0 = sigm(axr0 + ahr0), z0 = sigm(axz0 + ahz0);
        float n0 = tanhf(axn0 + r0 * ahn0);
        float hv0 = (1.f - z0) * n0 + z0 * hp0;
        float r1 = sigm(axr1 + ahr1), z1 = sigm(axz1 + ahz1);
        float n1 = tanhf(axn1 + r1 * ahn1);
        float hv1 = (1.f - z1) * n1 + z1 * hp1;

        hn[(size_t)b0*EH + jc] = hv0;
        hn[(size_t)b1*EH + jc] = hv1;

        grp_sync(cnt, (unsigned)((t + 1) * NGB));
    }
    // final h lands in slot0 (t=511 writes s0)
}

// ---------------- enc2gen linear + reparameterized IC sample --------------------------------------
__global__ __launch_bounds__(256) void ic_kernel(
    const float* __restrict__ henc,    // [B, EH] final encoder state (hbuf slot0)
    const float* __restrict__ W,       // [2*GH, EH]
    const float* __restrict__ eps,     // [B, GH]
    float*       __restrict__ out_icp, // [B, 2*GH]  (output #2)
    float*       __restrict__ gh0)     // [B, GH]    generator initial state (ping slot0)
{
    __shared__ float hb[EH];
    const int b = blockIdx.x, tid = threadIdx.x;
    for (int k = tid; k < EH; k += 256) hb[k] = henc[(size_t)b*EH + k];
    __syncthreads();

    for (int jj = tid; jj < GH; jj += 256) {
        const float4* wm = (const float4*)(W + (size_t)jj * EH);
        const float4* wl = (const float4*)(W + (size_t)(GH + jj) * EH);
        float am = 0.f, al = 0.f;
        #pragma unroll 4
        for (int k4 = 0; k4 < EH/4; ++k4) {
            float4 h = ((const float4*)hb)[k4];
            am += dot4(h, wm[k4]);
            al += dot4(h, wl[k4]);
        }
        out_icp[(size_t)b*2*GH + jj]      = am;
        out_icp[(size_t)b*2*GH + GH + jj] = al;
        gh0[(size_t)b*GH + jj] = am + __expf(0.5f * al) * eps[(size_t)b*GH + jj];
    }
}

// ---------------- Generator: modified GRU cell, 2 sync phases per step ----------------------------
__global__ __launch_bounds__(256, 1) void gen_kernel(
    const float* __restrict__ Wru,     // [2*GH, GH] rows: r then u
    const float* __restrict__ Wc,      // [GH, GH]
    float*       __restrict__ ghbuf,   // [2, B, GH] ping-pong, slot0 = ic
    float*       __restrict__ rh,      // [B, GH] r*h exchange buffer
    float*       __restrict__ out,     // [B, T, GH] (output #1)
    unsigned*    __restrict__ bars)
{
    __shared__ float sW[3][NB][WPAD];  // 0:r 1:u 2:c

    const int bid = blockIdx.x;
    const int g   = bid / NGB;
    const int ng  = bid % NGB;
    const int tid = threadIdx.x;
    const int j0  = ng * NB;

    for (int idx = tid; idx < NB * (GH/4); idx += 256) {
        int jj = idx >> 7;
        int k4 = idx & 127;
        *(float4*)&sW[0][jj][k4*4] = ((const float4*)(Wru + (size_t)(j0 + jj)      * GH))[k4];
        *(float4*)&sW[1][jj][k4*4] = ((const float4*)(Wru + (size_t)(GH + j0 + jj) * GH))[k4];
        *(float4*)&sW[2][jj][k4*4] = ((const float4*)(Wc  + (size_t)(j0 + jj)      * GH))[k4];
    }
    __syncthreads();

    const int bp = tid >> 4;
    const int j  = tid & 15;
    const int b0 = g*MB + bp*2, b1 = b0 + 1;
    const int jc = j0 + j;

    unsigned* cnt = bars + g * 32;
    float* s0 = ghbuf;
    float* s1 = ghbuf + (size_t)BB * GH;

    const float4* wrp = (const float4*)&sW[0][j][0];
    const float4* wup = (const float4*)&sW[1][j][0];
    const float4* wcp = (const float4*)&sW[2][j][0];

    for (int t = 0; t < TT; ++t) {
        const float* hc = (t & 1) ? s1 : s0;
        float*       hn = (t & 1) ? s0 : s1;

        // phase 1: r, u gates
        float ar0=0.f, au0=0.f, ar1=0.f, au1=0.f;
        const float4* h0p = (const float4*)(hc + (size_t)b0*GH);
        const float4* h1p = (const float4*)(hc + (size_t)b1*GH);
        float hp0 = hc[(size_t)b0*GH + jc];
        float hp1 = hc[(size_t)b1*GH + jc];
        #pragma unroll 4
        for (int k4 = 0; k4 < GH/4; ++k4) {
            float4 a0 = h0p[k4], a1 = h1p[k4];
            float4 r = wrp[k4], u = wup[k4];
            ar0 += dot4(a0,r); au0 += dot4(a0,u);
            ar1 += dot4(a1,r); au1 += dot4(a1,u);
        }
        float r0 = sigm(ar0), u0 = sigm(au0 + 1.0f);
        float r1 = sigm(ar1), u1 = sigm(au1 + 1.0f);
        rh[(size_t)b0*GH + jc] = r0 * hp0;
        rh[(size_t)b1*GH + jc] = r1 * hp1;

        grp_sync(cnt, (unsigned)((2*t + 1) * NGB));

        // phase 2: candidate c, combine, output
        float ac0=0.f, ac1=0.f;
        const float4* rh0 = (const float4*)(rh + (size_t)b0*GH);
        const float4* rh1 = (const float4*)(rh + (size_t)b1*GH);
        #pragma unroll 4
        for (int k4 = 0; k4 < GH/4; ++k4) {
            float4 c = wcp[k4];
            ac0 += dot4(rh0[k4], c);
            ac1 += dot4(rh1[k4], c);
        }
        float c0 = tanhf(ac0), c1 = tanhf(ac1);
        float hv0 = u0*hp0 + (1.f - u0)*c0;
        float hv1 = u1*hp1 + (1.f - u1)*c1;
        hn[(size_t)b0*GH + jc] = hv0;
        hn[(size_t)b1*GH + jc] = hv1;
        out[((size_t)b0*TT + t)*GH + jc] = fminf(fmaxf(hv0, -5.f), 5.f);
        out[((size_t)b1*TT + t)*GH + jc] = fminf(fmaxf(hv1, -5.f), 5.f);

        grp_sync(cnt, (unsigned)((2*t + 2) * NGB));
    }
}

extern "C" void kernel_launch(void* const* d_in, const int* in_sizes, int n_in,
                              void* d_out, int out_size, void* d_ws, size_t ws_size,
                              hipStream_t stream) {
    (void)in_sizes; (void)n_in; (void)out_size; (void)ws_size;

    const float* src    = (const float*)d_in[0];
    const float* eps    = (const float*)d_in[1];
    const float* enc_Wi = (const float*)d_in[2];
    const float* enc_Wh = (const float*)d_in[3];
    const float* e2g    = (const float*)d_in[4];
    const float* gWru   = (const float*)d_in[5];
    const float* gWc    = (const float*)d_in[6];
    float* out = (float*)d_out;

    // workspace layout (needs ~2.6 MB):
    // [0,8192)          barrier counters (enc at 0, gen at +4096 bytes)
    // [8192, +1MB)      encoder h ping-pong [2][B][EH]
    // [.., +1MB)        generator h ping-pong [2][B][GH]
    // [.., +512KB)      r*h exchange [B][GH]
    char* ws = (char*)d_ws;
    unsigned* bars = (unsigned*)ws;
    float* henc = (float*)(ws + 8192);
    float* ghb  = (float*)(ws + 8192 + (size_t)2*BB*EH*4);
    float* rhб  = (float*)(ws + 8192 + (size_t)4*BB*EH*4);

    hipMemsetAsync(ws, 0, 8192, stream);                        // reset barriers every call
    hipMemsetAsync(henc, 0, (size_t)BB*EH*4, stream);           // h0 = 0

    enc_kernel<<<dim3(NGROUP*NGB), dim3(256), 0, stream>>>(src, enc_Wi, enc_Wh, henc, bars);
    ic_kernel <<<dim3(BB),         dim3(256), 0, stream>>>(henc, e2g, eps,
                                                           out + (size_t)BB*TT*GH, ghb);
    gen_kernel<<<dim3(NGROUP*NGB), dim3(256), 0, stream>>>(gWru, gWc, ghb, rhб, out,
                                                           bars + 1024);
}